// Round 1
// baseline (682.994 us; speedup 1.0000x reference)
//
#include <hip/hip_runtime.h>

#define Bdim 8
#define Tdim 2048
#define Cdim 1024
#define CHUNK 128
#define NCHUNK 16
#define BC (Bdim*Cdim)

typedef float floatx4 __attribute__((ext_vector_type(4)));
typedef _Float16 half8 __attribute__((ext_vector_type(8)));
typedef _Float16 half4v __attribute__((ext_vector_type(4)));

// ---------------- Kernel 1: embedding gather + shift row, fp32 -> f16 ----------------
// xe[b][0][:] = xx_init[b], xe[b][1+t][:] = emb[tokens[b][t]]
__global__ __launch_bounds__(256) void embed_mix(const int* __restrict__ tokens,
                                                 const float* __restrict__ xx_init,
                                                 const float* __restrict__ emb,
                                                 _Float16* __restrict__ xe) {
    int row = blockIdx.x;              // 0 .. B*(T+1)-1
    int b = row / (Tdim + 1);
    int tt = row % (Tdim + 1);
    const float* src;
    if (tt == 0) src = xx_init + (size_t)b * Cdim;
    else         src = emb + (size_t)tokens[b * Tdim + tt - 1] * Cdim;
    int c0 = threadIdx.x * 4;
    float4 f = *reinterpret_cast<const float4*>(src + c0);
    half4v h;
    h[0] = (_Float16)f.x; h[1] = (_Float16)f.y; h[2] = (_Float16)f.z; h[3] = (_Float16)f.w;
    *reinterpret_cast<half4v*>(xe + (size_t)row * Cdim + c0) = h;
}

// ---------------- Kernel 2: fused k/v/r GEMM with on-the-fly time-mix ----------------
// out[m,n] = sum_c (mix[c]*x[m,c] + (1-mix[c])*xprev[m,c]) * W[n,c]
// blockIdx.z selects which of {k,v,r}; r gets sigmoid in epilogue.
__global__ __launch_bounds__(256) void gemm_kvr(const _Float16* __restrict__ xe,
                                                const float* __restrict__ Wk,
                                                const float* __restrict__ Wv,
                                                const float* __restrict__ Wr,
                                                const float* __restrict__ tmk,
                                                const float* __restrict__ tmv,
                                                const float* __restrict__ tmr,
                                                _Float16* __restrict__ ko,
                                                _Float16* __restrict__ vo,
                                                _Float16* __restrict__ ro) {
    const int which = blockIdx.z;
    const float* W   = which == 0 ? Wk  : (which == 1 ? Wv  : Wr);
    const float* mix = which == 0 ? tmk : (which == 1 ? tmv : tmr);
    _Float16* out    = which == 0 ? ko  : (which == 1 ? vo  : ro);

    const int m0 = blockIdx.x * 128;
    const int n0 = blockIdx.y * 128;

    // +8 pad: row stride 144B keeps 16B alignment, breaks b128 bank conflicts
    __shared__ _Float16 As[128][72];
    __shared__ _Float16 Bs[128][72];

    const int tid = threadIdx.x;
    const int lane = tid & 63;
    const int wave = tid >> 6;
    const int wm = (wave >> 1) * 64;
    const int wn = (wave & 1) * 64;

    // staging: 2 threads per row, 32 cols each
    const int srow = tid >> 1;
    const int scol = (tid & 1) * 32;
    const int m = m0 + srow;
    const int b = m >> 11;           // T = 2048
    const int t = m & 2047;
    const _Float16* curp = xe + ((size_t)(b * (Tdim + 1) + t + 1)) * Cdim;
    const _Float16* prvp = curp - Cdim;
    const float* wrow = W + (size_t)(n0 + srow) * Cdim;

    floatx4 acc[4][4] = {};

    for (int k0 = 0; k0 < Cdim; k0 += 64) {
        // stage A (time-mixed, f16)
        #pragma unroll
        for (int i = 0; i < 4; i++) {
            half8 cu = *reinterpret_cast<const half8*>(curp + k0 + scol + i * 8);
            half8 pv = *reinterpret_cast<const half8*>(prvp + k0 + scol + i * 8);
            half8 r8;
            #pragma unroll
            for (int jj = 0; jj < 8; jj++) {
                float mv = mix[k0 + scol + i * 8 + jj];
                float f = mv * (float)cu[jj] + (1.0f - mv) * (float)pv[jj];
                r8[jj] = (_Float16)f;
            }
            *reinterpret_cast<half8*>(&As[srow][scol + i * 8]) = r8;
        }
        // stage B (fp32 -> f16)
        #pragma unroll
        for (int i = 0; i < 4; i++) {
            float4 w0 = *reinterpret_cast<const float4*>(wrow + k0 + scol + i * 8);
            float4 w1 = *reinterpret_cast<const float4*>(wrow + k0 + scol + i * 8 + 4);
            half8 r8;
            r8[0] = (_Float16)w0.x; r8[1] = (_Float16)w0.y; r8[2] = (_Float16)w0.z; r8[3] = (_Float16)w0.w;
            r8[4] = (_Float16)w1.x; r8[5] = (_Float16)w1.y; r8[6] = (_Float16)w1.z; r8[7] = (_Float16)w1.w;
            *reinterpret_cast<half8*>(&Bs[srow][scol + i * 8]) = r8;
        }
        __syncthreads();
        #pragma unroll
        for (int kk = 0; kk < 64; kk += 32) {
            half8 af[4], bf[4];
            #pragma unroll
            for (int mi = 0; mi < 4; mi++)
                af[mi] = *reinterpret_cast<const half8*>(&As[wm + mi * 16 + (lane & 15)][kk + (lane >> 4) * 8]);
            #pragma unroll
            for (int ni = 0; ni < 4; ni++)
                bf[ni] = *reinterpret_cast<const half8*>(&Bs[wn + ni * 16 + (lane & 15)][kk + (lane >> 4) * 8]);
            #pragma unroll
            for (int mi = 0; mi < 4; mi++)
                #pragma unroll
                for (int ni = 0; ni < 4; ni++)
                    acc[mi][ni] = __builtin_amdgcn_mfma_f32_16x16x32_f16(af[mi], bf[ni], acc[mi][ni], 0, 0, 0);
        }
        __syncthreads();
    }

    // epilogue: C/D layout col = lane&15 (n), row = (lane>>4)*4 + reg (m)
    #pragma unroll
    for (int mi = 0; mi < 4; mi++) {
        #pragma unroll
        for (int ni = 0; ni < 4; ni++) {
            #pragma unroll
            for (int reg = 0; reg < 4; reg++) {
                int mm = m0 + wm + mi * 16 + (lane >> 4) * 4 + reg;
                int nn = n0 + wn + ni * 16 + (lane & 15);
                float v = acc[mi][ni][reg];
                if (which == 2) v = 1.0f / (1.0f + __expf(-v));
                out[(size_t)mm * Cdim + nn] = (_Float16)v;
            }
        }
    }
}

// ---------------- Kernel 3: chunk-local WKV totals (zero-start) ----------------
__global__ __launch_bounds__(256) void scan_pass1(const _Float16* __restrict__ kb,
                                                  const _Float16* __restrict__ vb,
                                                  const float* __restrict__ tdecay,
                                                  float* __restrict__ tot_a,
                                                  float* __restrict__ tot_b,
                                                  float* __restrict__ tot_p) {
    int idx = blockIdx.x * 256 + threadIdx.x;   // 0 .. NCHUNK*BC-1
    int j = idx >> 13;
    int bc = idx & (BC - 1);
    int b = bc >> 10;
    int c = bc & (Cdim - 1);
    float w = -__expf(tdecay[c]);
    float aa = 0.0f, bb = 0.0f, pp = -1e30f;
    const _Float16* kp = kb + ((size_t)(b * Tdim + j * CHUNK)) * Cdim + c;
    const _Float16* vp = vb + ((size_t)(b * Tdim + j * CHUNK)) * Cdim + c;
    #pragma unroll 4
    for (int t = 0; t < CHUNK; t++) {
        float kt = (float)kp[(size_t)t * Cdim];
        float vt = (float)vp[(size_t)t * Cdim];
        float ww2 = pp + w;
        float p2 = fmaxf(ww2, kt);
        float e1 = __expf(ww2 - p2);
        float e2 = __expf(kt - p2);
        aa = e1 * aa + e2 * vt;
        bb = e1 * bb + e2;
        pp = p2;
    }
    tot_a[idx] = aa; tot_b[idx] = bb; tot_p[idx] = pp;
}

// ---------------- Kernel 4: sequential combine of chunk totals -> incoming states ----------------
__global__ __launch_bounds__(256) void combine_chunks(const float* __restrict__ tot_a,
                                                      const float* __restrict__ tot_b,
                                                      const float* __restrict__ tot_p,
                                                      const float* __restrict__ aa_init,
                                                      const float* __restrict__ bb_init,
                                                      const float* __restrict__ pp_init,
                                                      const float* __restrict__ tdecay,
                                                      float* __restrict__ inc_a,
                                                      float* __restrict__ inc_b,
                                                      float* __restrict__ inc_p) {
    int idx = blockIdx.x * 256 + threadIdx.x;   // 0 .. BC-1
    int c = idx & (Cdim - 1);
    float w = -__expf(tdecay[c]);
    float wL = w * (float)CHUNK;
    float a = aa_init[idx], b = bb_init[idx], p = pp_init[idx];
    for (int j = 0; j < NCHUNK; j++) {
        inc_a[j * BC + idx] = a;
        inc_b[j * BC + idx] = b;
        inc_p[j * BC + idx] = p;
        float ta = tot_a[j * BC + idx];
        float tb = tot_b[j * BC + idx];
        float tp = tot_p[j * BC + idx];
        float px = p + wL;
        float q = fmaxf(px, tp);
        float e1 = __expf(px - q);
        float e2 = __expf(tp - q);
        a = e1 * a + e2 * ta;
        b = e1 * b + e2 * tb;
        p = q;
    }
}

// ---------------- Kernel 5: replay with incoming state, emit y = r*wkv reductions ----------------
__global__ __launch_bounds__(256) void scan_pass2(const _Float16* __restrict__ kb,
                                                  const _Float16* __restrict__ vb,
                                                  const _Float16* __restrict__ rb,
                                                  const float* __restrict__ tdecay,
                                                  const float* __restrict__ tfirst,
                                                  const float* __restrict__ inc_a,
                                                  const float* __restrict__ inc_b,
                                                  const float* __restrict__ inc_p,
                                                  float* __restrict__ partial,
                                                  float* __restrict__ ylast) {
    int idx = blockIdx.x * 256 + threadIdx.x;
    int j = idx >> 13;
    int bc = idx & (BC - 1);
    int b = bc >> 10;
    int c = bc & (Cdim - 1);
    float w = -__expf(tdecay[c]);
    float u = tfirst[c];
    float aa = inc_a[idx], bb = inc_b[idx], pp = inc_p[idx];
    const size_t base = ((size_t)(b * Tdim + j * CHUNK)) * Cdim + c;
    const _Float16* kp = kb + base;
    const _Float16* vp = vb + base;
    const _Float16* rp = rb + base;
    float sum = 0.0f, ylv = 0.0f;
    #pragma unroll 4
    for (int t = 0; t < CHUNK; t++) {
        float kt = (float)kp[(size_t)t * Cdim];
        float vt = (float)vp[(size_t)t * Cdim];
        float rt = (float)rp[(size_t)t * Cdim];
        // output (uses pre-update state)
        float ww = u + kt;
        float p = fmaxf(pp, ww);
        float e1 = __expf(pp - p);
        float e2 = __expf(ww - p);
        float wkv = (e1 * aa + e2 * vt) / (e1 * bb + e2);
        float y = rt * wkv;
        sum += y;
        ylv = y;
        // state update
        float ww2 = pp + w;
        float p2 = fmaxf(ww2, kt);
        float e1b = __expf(ww2 - p2);
        float e2b = __expf(kt - p2);
        aa = e1b * aa + e2b * vt;
        bb = e1b * bb + e2b;
        pp = p2;
    }
    partial[idx] = sum;
    if (j == NCHUNK - 1) ylast[bc] = ylv;
}

// ---------------- Kernel 6: z[b,c] = 0.5*(y_last + mean_t y) ----------------
__global__ __launch_bounds__(256) void reduce_z(const float* __restrict__ partial,
                                                const float* __restrict__ ylast,
                                                float* __restrict__ z) {
    int idx = blockIdx.x * 256 + threadIdx.x;   // 0..BC-1
    float s = 0.0f;
    for (int j = 0; j < NCHUNK; j++) s += partial[j * BC + idx];
    z[idx] = 0.5f * (ylast[idx] + s * (1.0f / (float)Tdim));
}

// ---------------- Kernel 7: hx[b,d] = sum_c z[b,c]*Wo[d,c]; write twice ----------------
__global__ __launch_bounds__(256) void final_out(const float* __restrict__ z,
                                                 const float* __restrict__ Wo,
                                                 float* __restrict__ out) {
    int gw = (blockIdx.x * 256 + threadIdx.x) >> 6;   // global wave id, 0..BC-1
    int lane = threadIdx.x & 63;
    int b = gw >> 10;
    int d = gw & (Cdim - 1);
    const float* zr = z + (size_t)b * Cdim;
    const float* wr = Wo + (size_t)d * Cdim;
    float acc = 0.0f;
    #pragma unroll
    for (int i = lane; i < Cdim; i += 64) acc += zr[i] * wr[i];
    #pragma unroll
    for (int off = 32; off > 0; off >>= 1) acc += __shfl_down(acc, off);
    if (lane == 0) {
        out[(size_t)b * Cdim + d] = acc;
        out[(size_t)BC + (size_t)b * Cdim + d] = acc;
    }
}

extern "C" void kernel_launch(void* const* d_in, const int* in_sizes, int n_in,
                              void* d_out, int out_size, void* d_ws, size_t ws_size,
                              hipStream_t stream) {
    const int*   tokens  = (const int*)d_in[0];
    const float* xx_init = (const float*)d_in[1];
    const float* aa_init = (const float*)d_in[2];
    const float* bb_init = (const float*)d_in[3];
    const float* pp_init = (const float*)d_in[4];
    const float* emb     = (const float*)d_in[5];
    const float* tmk     = (const float*)d_in[6];
    const float* tmv     = (const float*)d_in[7];
    const float* tmr     = (const float*)d_in[8];
    const float* tdecay  = (const float*)d_in[9];
    const float* tfirst  = (const float*)d_in[10];
    const float* Wk      = (const float*)d_in[11];
    const float* Wv      = (const float*)d_in[12];
    const float* Wr      = (const float*)d_in[13];
    const float* Wo      = (const float*)d_in[14];
    float* out = (float*)d_out;

    char* ws = (char*)d_ws;
    size_t off = 0;
    auto alloc = [&](size_t bytes) -> void* {
        void* p = ws + off;
        off += (bytes + 255) & ~(size_t)255;
        return p;
    };
    _Float16* xe = (_Float16*)alloc((size_t)Bdim * (Tdim + 1) * Cdim * 2);
    _Float16* kb = (_Float16*)alloc((size_t)Bdim * Tdim * Cdim * 2);
    _Float16* vb = (_Float16*)alloc((size_t)Bdim * Tdim * Cdim * 2);
    _Float16* rb = (_Float16*)alloc((size_t)Bdim * Tdim * Cdim * 2);
    float* tot_a = (float*)alloc((size_t)NCHUNK * BC * 4);
    float* tot_b = (float*)alloc((size_t)NCHUNK * BC * 4);
    float* tot_p = (float*)alloc((size_t)NCHUNK * BC * 4);
    float* inc_a = (float*)alloc((size_t)NCHUNK * BC * 4);
    float* inc_b = (float*)alloc((size_t)NCHUNK * BC * 4);
    float* inc_p = (float*)alloc((size_t)NCHUNK * BC * 4);
    float* partial = (float*)alloc((size_t)NCHUNK * BC * 4);
    float* ylast   = (float*)alloc((size_t)BC * 4);
    float* zbuf    = (float*)alloc((size_t)BC * 4);

    embed_mix<<<Bdim * (Tdim + 1), 256, 0, stream>>>(tokens, xx_init, emb, xe);
    gemm_kvr<<<dim3(128, 8, 3), 256, 0, stream>>>(xe, Wk, Wv, Wr, tmk, tmv, tmr, kb, vb, rb);
    scan_pass1<<<(NCHUNK * BC) / 256, 256, 0, stream>>>(kb, vb, tdecay, tot_a, tot_b, tot_p);
    combine_chunks<<<BC / 256, 256, 0, stream>>>(tot_a, tot_b, tot_p, aa_init, bb_init, pp_init,
                                                 tdecay, inc_a, inc_b, inc_p);
    scan_pass2<<<(NCHUNK * BC) / 256, 256, 0, stream>>>(kb, vb, rb, tdecay, tfirst,
                                                        inc_a, inc_b, inc_p, partial, ylast);
    reduce_z<<<BC / 256, 256, 0, stream>>>(partial, ylast, zbuf);
    final_out<<<(BC / 4), 256, 0, stream>>>(zbuf, Wo, out);
}

// Round 2
// 414.472 us; speedup vs baseline: 1.6479x; 1.6479x over previous
//
#include <hip/hip_runtime.h>

#define Bdim 8
#define Tdim 2048
#define Cdim 1024
#define CHUNK 128
#define NCHUNK 16
#define BC (Bdim*Cdim)

typedef float floatx4 __attribute__((ext_vector_type(4)));
typedef _Float16 half8 __attribute__((ext_vector_type(8)));
typedef _Float16 half4v __attribute__((ext_vector_type(4)));

__device__ __forceinline__ void load16(const void* g, void* l) {
    __builtin_amdgcn_global_load_lds(
        (const __attribute__((address_space(1))) void*)g,
        (__attribute__((address_space(3))) void*)l, 16, 0, 0);
}

// ---------------- Kernel 1: embedding gather + shift row, fp32 -> f16 ----------------
__global__ __launch_bounds__(256) void embed_mix(const int* __restrict__ tokens,
                                                 const float* __restrict__ xx_init,
                                                 const float* __restrict__ emb,
                                                 _Float16* __restrict__ xe) {
    int row = blockIdx.x;              // 0 .. B*(T+1)-1
    int b = row / (Tdim + 1);
    int tt = row % (Tdim + 1);
    const float* src;
    if (tt == 0) src = xx_init + (size_t)b * Cdim;
    else         src = emb + (size_t)tokens[b * Tdim + tt - 1] * Cdim;
    int c0 = threadIdx.x * 4;
    float4 f = *reinterpret_cast<const float4*>(src + c0);
    half4v h;
    h[0] = (_Float16)f.x; h[1] = (_Float16)f.y; h[2] = (_Float16)f.z; h[3] = (_Float16)f.w;
    *reinterpret_cast<half4v*>(xe + (size_t)row * Cdim + c0) = h;
}

// ---------------- Kernel 1b: time-mix precompute, f16 in -> f16 out (x3) ----------------
__global__ __launch_bounds__(256) void mix3(const _Float16* __restrict__ xe,
                                            const float* __restrict__ tmk,
                                            const float* __restrict__ tmv,
                                            const float* __restrict__ tmr,
                                            _Float16* __restrict__ xk,
                                            _Float16* __restrict__ xv,
                                            _Float16* __restrict__ xr) {
    int row = blockIdx.x;              // b*T + t
    int b = row >> 11;
    int t = row & (Tdim - 1);
    const _Float16* cur = xe + ((size_t)(b * (Tdim + 1) + t + 1)) * Cdim;
    const _Float16* prv = cur - Cdim;
    int c = threadIdx.x * 4;
    half4v cu = *reinterpret_cast<const half4v*>(cur + c);
    half4v pv = *reinterpret_cast<const half4v*>(prv + c);
    float4 mk = *reinterpret_cast<const float4*>(tmk + c);
    float4 mv = *reinterpret_cast<const float4*>(tmv + c);
    float4 mr = *reinterpret_cast<const float4*>(tmr + c);
    half4v hk, hv, hr;
    float cf[4] = {(float)cu[0], (float)cu[1], (float)cu[2], (float)cu[3]};
    float pf[4] = {(float)pv[0], (float)pv[1], (float)pv[2], (float)pv[3]};
    float mkf[4] = {mk.x, mk.y, mk.z, mk.w};
    float mvf[4] = {mv.x, mv.y, mv.z, mv.w};
    float mrf[4] = {mr.x, mr.y, mr.z, mr.w};
    #pragma unroll
    for (int j = 0; j < 4; j++) {
        hk[j] = (_Float16)(mkf[j] * cf[j] + (1.0f - mkf[j]) * pf[j]);
        hv[j] = (_Float16)(mvf[j] * cf[j] + (1.0f - mvf[j]) * pf[j]);
        hr[j] = (_Float16)(mrf[j] * cf[j] + (1.0f - mrf[j]) * pf[j]);
    }
    size_t o = (size_t)row * Cdim + c;
    *reinterpret_cast<half4v*>(xk + o) = hk;
    *reinterpret_cast<half4v*>(xv + o) = hv;
    *reinterpret_cast<half4v*>(xr + o) = hr;
}

// ---------------- Kernel 1c: W fp32 -> f16 ----------------
__global__ __launch_bounds__(256) void wconv(const float* __restrict__ Wk,
                                             const float* __restrict__ Wv,
                                             const float* __restrict__ Wr,
                                             _Float16* __restrict__ Wh) {
    const float* W = blockIdx.y == 0 ? Wk : (blockIdx.y == 1 ? Wv : Wr);
    _Float16* dst = Wh + (size_t)blockIdx.y * Cdim * Cdim;
    int i = (blockIdx.x * 256 + threadIdx.x) * 4;
    float4 f = *reinterpret_cast<const float4*>(W + i);
    half4v h;
    h[0] = (_Float16)f.x; h[1] = (_Float16)f.y; h[2] = (_Float16)f.z; h[3] = (_Float16)f.w;
    *reinterpret_cast<half4v*>(dst + i) = h;
}

// ---------------- Kernel 2: m97-style f16 GEMM (NT), 128x128 tile, BK=64 ----------------
// out[m,n] = sum_c X[m,c] * W[n,c];  which=2 gets sigmoid.
__global__ __launch_bounds__(256) void gemm_kvr(const _Float16* __restrict__ xk,
                                                const _Float16* __restrict__ xv,
                                                const _Float16* __restrict__ xr,
                                                const _Float16* __restrict__ Wh,
                                                _Float16* __restrict__ ko,
                                                _Float16* __restrict__ vo,
                                                _Float16* __restrict__ ro) {
    const int which = blockIdx.y;
    const _Float16* X = which == 0 ? xk : (which == 1 ? xv : xr);
    const _Float16* W = Wh + (size_t)which * Cdim * Cdim;
    _Float16* out     = which == 0 ? ko : (which == 1 ? vo : ro);

    // XCD-aware swizzle: all 8 n-tiles of one m-tile on the same XCD
    const int lin = blockIdx.x;        // 0..1023
    const int xcd = lin & 7;
    const int loc = lin >> 3;          // 0..127
    const int mt = xcd * 16 + (loc >> 3);
    const int nt = loc & 7;
    const int m0 = mt * 128;
    const int n0 = nt * 128;

    __shared__ _Float16 As[128 * 64];
    __shared__ _Float16 Bs[128 * 64];

    const int tid = threadIdx.x;
    const int lane = tid & 63;
    const int wave = tid >> 6;
    const int wm = (wave >> 1) * 64;
    const int wn = (wave & 1) * 64;
    const int lr = lane & 15;          // fragment row within 16
    const int lk = lane >> 4;          // fragment k-block 0..3

    const _Float16* Asrc = X + (size_t)m0 * Cdim;
    const _Float16* Bsrc = W + (size_t)n0 * Cdim;

    floatx4 acc[4][4] = {};

    for (int k0 = 0; k0 < Cdim; k0 += 64) {
        #pragma unroll
        for (int i = 0; i < 4; i++) {
            int e = i * 256 + tid;     // 16B slot index, 0..1023
            int r = e >> 3;            // tile row
            int cbp = e & 7;           // physical colblock
            int cbl = cbp ^ (r & 7);   // logical colblock (XOR swizzle)
            load16(Asrc + (size_t)r * Cdim + k0 + cbl * 8, (char*)As + e * 16);
            load16(Bsrc + (size_t)r * Cdim + k0 + cbl * 8, (char*)Bs + e * 16);
        }
        __syncthreads();
        #pragma unroll
        for (int kk = 0; kk < 64; kk += 32) {
            const int kb_ = kk >> 3;
            half8 af[4], bf[4];
            #pragma unroll
            for (int mi = 0; mi < 4; mi++) {
                int r = wm + mi * 16 + lr;
                int cb = (kb_ + lk) ^ (r & 7);
                af[mi] = *reinterpret_cast<const half8*>(As + r * 64 + cb * 8);
            }
            #pragma unroll
            for (int ni = 0; ni < 4; ni++) {
                int r = wn + ni * 16 + lr;
                int cb = (kb_ + lk) ^ (r & 7);
                bf[ni] = *reinterpret_cast<const half8*>(Bs + r * 64 + cb * 8);
            }
            #pragma unroll
            for (int mi = 0; mi < 4; mi++)
                #pragma unroll
                for (int ni = 0; ni < 4; ni++)
                    acc[mi][ni] = __builtin_amdgcn_mfma_f32_16x16x32_f16(af[mi], bf[ni], acc[mi][ni], 0, 0, 0);
        }
        __syncthreads();
    }

    // epilogue: C/D layout col = lane&15 (n), row = (lane>>4)*4 + reg (m)
    #pragma unroll
    for (int mi = 0; mi < 4; mi++) {
        #pragma unroll
        for (int ni = 0; ni < 4; ni++) {
            #pragma unroll
            for (int reg = 0; reg < 4; reg++) {
                int mm = m0 + wm + mi * 16 + (lane >> 4) * 4 + reg;
                int nn = n0 + wn + ni * 16 + (lane & 15);
                float v = acc[mi][ni][reg];
                if (which == 2) v = 1.0f / (1.0f + __expf(-v));
                out[(size_t)mm * Cdim + nn] = (_Float16)v;
            }
        }
    }
}

// ---------------- Kernel 3: chunk-local WKV totals (zero-start) ----------------
__global__ __launch_bounds__(256) void scan_pass1(const _Float16* __restrict__ kb,
                                                  const _Float16* __restrict__ vb,
                                                  const float* __restrict__ tdecay,
                                                  float* __restrict__ tot_a,
                                                  float* __restrict__ tot_b,
                                                  float* __restrict__ tot_p) {
    int idx = blockIdx.x * 256 + threadIdx.x;   // 0 .. NCHUNK*BC-1
    int j = idx >> 13;
    int bc = idx & (BC - 1);
    int b = bc >> 10;
    int c = bc & (Cdim - 1);
    float w = -__expf(tdecay[c]);
    float aa = 0.0f, bb = 0.0f, pp = -1e30f;
    const _Float16* kp = kb + ((size_t)(b * Tdim + j * CHUNK)) * Cdim + c;
    const _Float16* vp = vb + ((size_t)(b * Tdim + j * CHUNK)) * Cdim + c;
    #pragma unroll 4
    for (int t = 0; t < CHUNK; t++) {
        float kt = (float)kp[(size_t)t * Cdim];
        float vt = (float)vp[(size_t)t * Cdim];
        float ww2 = pp + w;
        float p2 = fmaxf(ww2, kt);
        float e1 = __expf(ww2 - p2);
        float e2 = __expf(kt - p2);
        aa = e1 * aa + e2 * vt;
        bb = e1 * bb + e2;
        pp = p2;
    }
    tot_a[idx] = aa; tot_b[idx] = bb; tot_p[idx] = pp;
}

// ---------------- Kernel 4: sequential combine of chunk totals ----------------
__global__ __launch_bounds__(256) void combine_chunks(const float* __restrict__ tot_a,
                                                      const float* __restrict__ tot_b,
                                                      const float* __restrict__ tot_p,
                                                      const float* __restrict__ aa_init,
                                                      const float* __restrict__ bb_init,
                                                      const float* __restrict__ pp_init,
                                                      const float* __restrict__ tdecay,
                                                      float* __restrict__ inc_a,
                                                      float* __restrict__ inc_b,
                                                      float* __restrict__ inc_p) {
    int idx = blockIdx.x * 256 + threadIdx.x;   // 0 .. BC-1
    int c = idx & (Cdim - 1);
    float w = -__expf(tdecay[c]);
    float wL = w * (float)CHUNK;
    float a = aa_init[idx], b = bb_init[idx], p = pp_init[idx];
    for (int j = 0; j < NCHUNK; j++) {
        inc_a[j * BC + idx] = a;
        inc_b[j * BC + idx] = b;
        inc_p[j * BC + idx] = p;
        float ta = tot_a[j * BC + idx];
        float tb = tot_b[j * BC + idx];
        float tp = tot_p[j * BC + idx];
        float px = p + wL;
        float q = fmaxf(px, tp);
        float e1 = __expf(px - q);
        float e2 = __expf(tp - q);
        a = e1 * a + e2 * ta;
        b = e1 * b + e2 * tb;
        p = q;
    }
}

// ---------------- Kernel 5: replay with incoming state ----------------
__global__ __launch_bounds__(256) void scan_pass2(const _Float16* __restrict__ kb,
                                                  const _Float16* __restrict__ vb,
                                                  const _Float16* __restrict__ rb,
                                                  const float* __restrict__ tdecay,
                                                  const float* __restrict__ tfirst,
                                                  const float* __restrict__ inc_a,
                                                  const float* __restrict__ inc_b,
                                                  const float* __restrict__ inc_p,
                                                  float* __restrict__ partial,
                                                  float* __restrict__ ylast) {
    int idx = blockIdx.x * 256 + threadIdx.x;
    int j = idx >> 13;
    int bc = idx & (BC - 1);
    int b = bc >> 10;
    int c = bc & (Cdim - 1);
    float w = -__expf(tdecay[c]);
    float u = tfirst[c];
    float aa = inc_a[idx], bb = inc_b[idx], pp = inc_p[idx];
    const size_t base = ((size_t)(b * Tdim + j * CHUNK)) * Cdim + c;
    const _Float16* kp = kb + base;
    const _Float16* vp = vb + base;
    const _Float16* rp = rb + base;
    float sum = 0.0f, ylv = 0.0f;
    #pragma unroll 4
    for (int t = 0; t < CHUNK; t++) {
        float kt = (float)kp[(size_t)t * Cdim];
        float vt = (float)vp[(size_t)t * Cdim];
        float rt = (float)rp[(size_t)t * Cdim];
        float ww = u + kt;
        float p = fmaxf(pp, ww);
        float e1 = __expf(pp - p);
        float e2 = __expf(ww - p);
        float wkv = (e1 * aa + e2 * vt) / (e1 * bb + e2);
        float y = rt * wkv;
        sum += y;
        ylv = y;
        float ww2 = pp + w;
        float p2 = fmaxf(ww2, kt);
        float e1b = __expf(ww2 - p2);
        float e2b = __expf(kt - p2);
        aa = e1b * aa + e2b * vt;
        bb = e1b * bb + e2b;
        pp = p2;
    }
    partial[idx] = sum;
    if (j == NCHUNK - 1) ylast[bc] = ylv;
}

// ---------------- Kernel 6: z[b,c] = 0.5*(y_last + mean_t y) ----------------
__global__ __launch_bounds__(256) void reduce_z(const float* __restrict__ partial,
                                                const float* __restrict__ ylast,
                                                float* __restrict__ z) {
    int idx = blockIdx.x * 256 + threadIdx.x;   // 0..BC-1
    float s = 0.0f;
    for (int j = 0; j < NCHUNK; j++) s += partial[j * BC + idx];
    z[idx] = 0.5f * (ylast[idx] + s * (1.0f / (float)Tdim));
}

// ---------------- Kernel 7: hx[b,d] = sum_c z[b,c]*Wo[d,c]; write twice ----------------
__global__ __launch_bounds__(256) void final_out(const float* __restrict__ z,
                                                 const float* __restrict__ Wo,
                                                 float* __restrict__ out) {
    int gw = (blockIdx.x * 256 + threadIdx.x) >> 6;   // global wave id, 0..BC-1
    int lane = threadIdx.x & 63;
    int b = gw >> 10;
    int d = gw & (Cdim - 1);
    const float* zr = z + (size_t)b * Cdim;
    const float* wr = Wo + (size_t)d * Cdim;
    float acc = 0.0f;
    #pragma unroll
    for (int i = lane; i < Cdim; i += 64) acc += zr[i] * wr[i];
    #pragma unroll
    for (int off = 32; off > 0; off >>= 1) acc += __shfl_down(acc, off);
    if (lane == 0) {
        out[(size_t)b * Cdim + d] = acc;
        out[(size_t)BC + (size_t)b * Cdim + d] = acc;
    }
}

extern "C" void kernel_launch(void* const* d_in, const int* in_sizes, int n_in,
                              void* d_out, int out_size, void* d_ws, size_t ws_size,
                              hipStream_t stream) {
    const int*   tokens  = (const int*)d_in[0];
    const float* xx_init = (const float*)d_in[1];
    const float* aa_init = (const float*)d_in[2];
    const float* bb_init = (const float*)d_in[3];
    const float* pp_init = (const float*)d_in[4];
    const float* emb     = (const float*)d_in[5];
    const float* tmk     = (const float*)d_in[6];
    const float* tmv     = (const float*)d_in[7];
    const float* tmr     = (const float*)d_in[8];
    const float* tdecay  = (const float*)d_in[9];
    const float* tfirst  = (const float*)d_in[10];
    const float* Wk      = (const float*)d_in[11];
    const float* Wv      = (const float*)d_in[12];
    const float* Wr      = (const float*)d_in[13];
    const float* Wo      = (const float*)d_in[14];
    float* out = (float*)d_out;

    char* ws = (char*)d_ws;
    size_t off = 0;
    auto alloc = [&](size_t bytes) -> void* {
        void* p = ws + off;
        off += (bytes + 255) & ~(size_t)255;
        return p;
    };
    _Float16* xe = (_Float16*)alloc((size_t)Bdim * (Tdim + 1) * Cdim * 2);
    _Float16* xkb = (_Float16*)alloc((size_t)Bdim * Tdim * Cdim * 2);
    _Float16* xvb = (_Float16*)alloc((size_t)Bdim * Tdim * Cdim * 2);
    _Float16* xrb = (_Float16*)alloc((size_t)Bdim * Tdim * Cdim * 2);
    _Float16* kb = xe;   // alias: xe dead after mix3
    _Float16* vb = (_Float16*)alloc((size_t)Bdim * Tdim * Cdim * 2);
    _Float16* rb = (_Float16*)alloc((size_t)Bdim * Tdim * Cdim * 2);
    _Float16* Wh = (_Float16*)alloc((size_t)3 * Cdim * Cdim * 2);
    float* tot_a = (float*)alloc((size_t)NCHUNK * BC * 4);
    float* tot_b = (float*)alloc((size_t)NCHUNK * BC * 4);
    float* tot_p = (float*)alloc((size_t)NCHUNK * BC * 4);
    float* inc_a = (float*)alloc((size_t)NCHUNK * BC * 4);
    float* inc_b = (float*)alloc((size_t)NCHUNK * BC * 4);
    float* inc_p = (float*)alloc((size_t)NCHUNK * BC * 4);
    float* partial = (float*)alloc((size_t)NCHUNK * BC * 4);
    float* ylast   = (float*)alloc((size_t)BC * 4);
    float* zbuf    = (float*)alloc((size_t)BC * 4);

    embed_mix<<<Bdim * (Tdim + 1), 256, 0, stream>>>(tokens, xx_init, emb, xe);
    mix3<<<Bdim * Tdim, 256, 0, stream>>>(xe, tmk, tmv, tmr, xkb, xvb, xrb);
    wconv<<<dim3(1024, 3), 256, 0, stream>>>(Wk, Wv, Wr, Wh);
    gemm_kvr<<<dim3(1024, 3), 256, 0, stream>>>(xkb, xvb, xrb, Wh, kb, vb, rb);
    scan_pass1<<<(NCHUNK * BC) / 256, 256, 0, stream>>>(kb, vb, tdecay, tot_a, tot_b, tot_p);
    combine_chunks<<<BC / 256, 256, 0, stream>>>(tot_a, tot_b, tot_p, aa_init, bb_init, pp_init,
                                                 tdecay, inc_a, inc_b, inc_p);
    scan_pass2<<<(NCHUNK * BC) / 256, 256, 0, stream>>>(kb, vb, rb, tdecay, tfirst,
                                                        inc_a, inc_b, inc_p, partial, ylast);
    reduce_z<<<BC / 256, 256, 0, stream>>>(partial, ylast, zbuf);
    final_out<<<(BC / 4), 256, 0, stream>>>(zbuf, Wo, out);
}